// Round 2
// baseline (86935.016 us; speedup 1.0000x reference)
//
#include <hip/hip_runtime.h>
#include <hip/hip_cooperative_groups.h>

namespace cg = cooperative_groups;

#define Bz 32
#define Tz 256
#define Hz 512
#define Nz 5
#define Rz 2
#define Wz 512
#define RWz 1024
#define XD 1536          // H + R*W
#define IFz 2573         // R*W + 3*W + 5*R + 3
#define EPSF 1e-6f
#define NWG 256
#define NT 1024
#define NTH (NWG*NT)     // 262144

// xi field offsets
#define O_KR 0
#define O_BR 1024
#define O_KW 1026
#define O_BW 1538
#define O_E  1539
#define O_V  2051
#define O_FG 2563
#define O_GA 2565
#define O_GW 2566
#define O_PI 2567

__device__ __forceinline__ float sigf(float x){ return 1.0f/(1.0f+expf(-x)); }
__device__ __forceinline__ float splus(float x){ return fmaxf(x,0.0f) + log1pf(expf(-fabsf(x))); }

// contiguous-x · contiguous-w dot, float4 both sides, n % 16 == 0
__device__ __forceinline__ float dot4(const float* __restrict__ x,
                                      const float* __restrict__ w, int n){
  const float4* x4 = (const float4*)x;
  const float4* w4 = (const float4*)w;
  float a0=0.f,a1=0.f,a2=0.f,a3=0.f;
  #pragma unroll 4
  for (int k=0;k<n/4;k++){
    float4 xv = x4[k], wv = w4[k];
    a0 = fmaf(xv.x,wv.x,a0); a1 = fmaf(xv.y,wv.y,a1);
    a2 = fmaf(xv.z,wv.z,a2); a3 = fmaf(xv.w,wv.w,a3);
  }
  return (a0+a1)+(a2+a3);
}

__device__ void memops(int b, int t, const float* xiT,
                       float* Mg, float* ug, float* pg, float* wwg, float* Lg, float* wrg,
                       float* rT)
{
  __shared__ float s_xi[IFz];
  __shared__ float s_M[Nz*Wz];
  __shared__ float s_u[Nz], s_p[Nz], s_ww[Nz], s_a[Nz], s_L[Nz*Nz], s_wr[Rz*Nz];
  __shared__ float s_sc[13]; // 0:br0 1:br1 2:bw 3:fg0 4:fg1 5:ga 6:gw 7..12:pi
  __shared__ float s_m2[Nz], s_dt[Nz], s_d0[Nz], s_d1[Nz];
  __shared__ float s_kw2, s_kr2[2];
  __shared__ float s_fwd[Rz*Nz], s_bwd[Rz*Nz];

  const int tid = threadIdx.x;
  const int wv = tid >> 6, ln = tid & 63;

  for (int f = tid; f < IFz; f += NT) s_xi[f] = xiT[(size_t)b*IFz + f];
  for (int i = tid; i < Nz*Wz; i += NT) s_M[i] = Mg[(size_t)b*Nz*Wz + i];
  if (tid < Nz){ s_u[tid]=ug[b*Nz+tid]; s_p[tid]=pg[b*Nz+tid]; s_ww[tid]=wwg[b*Nz+tid]; }
  if (tid < Nz*Nz) s_L[tid] = Lg[b*Nz*Nz+tid];
  if (tid < Rz*Nz) s_wr[tid] = wrg[b*Rz*Nz+tid];
  __syncthreads();

  if (tid == 0){
    s_sc[0] = 1.0f + splus(s_xi[O_BR+0]);
    s_sc[1] = 1.0f + splus(s_xi[O_BR+1]);
    s_sc[2] = 1.0f + splus(s_xi[O_BW]);
    s_sc[3] = sigf(s_xi[O_FG+0]);
    s_sc[4] = sigf(s_xi[O_FG+1]);
    s_sc[5] = sigf(s_xi[O_GA]);
    s_sc[6] = sigf(s_xi[O_GW]);
    for (int r=0;r<Rz;r++){
      float x0=s_xi[O_PI+r*3+0], x1=s_xi[O_PI+r*3+1], x2=s_xi[O_PI+r*3+2];
      float m = fmaxf(x0,fmaxf(x1,x2));
      float e0=expf(x0-m), e1=expf(x1-m), e2=expf(x2-m);
      float s = e0+e1+e2;
      s_sc[7+r*3+0]=e0/s; s_sc[7+r*3+1]=e1/s; s_sc[7+r*3+2]=e2/s;
    }
  }
  __syncthreads();

  // psi & usage update (uses OLD ww, OLD wr)
  if (tid < Nz){
    float psi = (1.0f - s_sc[3]*s_wr[0*Nz+tid]) * (1.0f - s_sc[4]*s_wr[1*Nz+tid]);
    float uu = s_u[tid], w = s_ww[tid];
    s_u[tid] = (uu + w - uu*w) * psi;
  }

  // cosine(M_old, kw): per-wave fused dot + ||M_n||^2  (waves 0..4 -> n, wave 5 -> ||kw||^2)
  if (wv < Nz){
    const int n = wv;
    float pd=0.f, pm=0.f;
    for (int w = ln; w < Wz; w += 64){
      float kv = s_xi[O_KW+w], mv = s_M[n*Wz+w];
      pd = fmaf(kv,mv,pd); pm = fmaf(mv,mv,pm);
    }
    for (int off=32; off; off>>=1){ pd += __shfl_down(pd,off,64); pm += __shfl_down(pm,off,64); }
    if (ln==0){ s_dt[n]=pd; s_m2[n]=pm; }
  } else if (wv == 5){
    float p2=0.f;
    for (int w=ln; w<Wz; w+=64){ float kv=s_xi[O_KW+w]; p2=fmaf(kv,kv,p2); }
    for (int off=32; off; off>>=1) p2 += __shfl_down(p2,off,64);
    if (ln==0) s_kw2 = p2;
  }
  __syncthreads();

  if (tid == 0){
    // allocation weights from updated u (stable ascending argsort, N=5)
    float su[Nz]; int idx[Nz];
    for (int i=0;i<Nz;i++){
      float v = EPSF + (1.0f-EPSF)*s_u[i];
      int j=i;
      while (j>0 && su[j-1] > v){ su[j]=su[j-1]; idx[j]=idx[j-1]; j--; }
      su[j]=v; idx[j]=i;
    }
    float cp = 1.0f;
    for (int k=0;k<Nz;k++){ s_a[idx[k]] = (1.0f - su[k])*cp; cp *= su[k]; }
    // content write weights
    float rk = rsqrtf(s_kw2 + EPSF);
    float lg[Nz], mx=-1e30f;
    for (int n=0;n<Nz;n++){ lg[n] = s_sc[2]*s_dt[n]*rk*rsqrtf(s_m2[n]+EPSF); mx=fmaxf(mx,lg[n]); }
    float ssum=0.f;
    for (int n=0;n<Nz;n++){ lg[n]=expf(lg[n]-mx); ssum+=lg[n]; }
    float ga=s_sc[5], gw=s_sc[6];
    for (int n=0;n<Nz;n++){ float cwn = lg[n]/ssum; s_ww[n] = gw*(ga*s_a[n] + (1.0f-ga)*cwn); }
  }
  __syncthreads();

  // memory write
  for (int i = tid; i < Nz*Wz; i += NT){
    int n = i >> 9, w = i & 511;
    float e = sigf(s_xi[O_E+w]);
    float v = s_xi[O_V+w];
    s_M[i] = s_M[i]*(1.0f - s_ww[n]*e) + s_ww[n]*v;
  }
  __syncthreads();

  // link matrix, precedence, fwd/bwd (tiny, serial)
  if (tid == 0){
    float wsum = 0.f;
    for (int n=0;n<Nz;n++) wsum += s_ww[n];
    float Lo[Nz*Nz];
    for (int i=0;i<Nz;i++)
      for (int j=0;j<Nz;j++)
        Lo[i*Nz+j] = (i==j) ? 0.0f : ((1.0f - s_ww[i] - s_ww[j])*s_L[i*Nz+j] + s_ww[i]*s_p[j]);
    for (int i=0;i<Nz*Nz;i++) s_L[i]=Lo[i];
    for (int j=0;j<Nz;j++) s_p[j] = (1.0f-wsum)*s_p[j] + s_ww[j];
    for (int r=0;r<Rz;r++)
      for (int n=0;n<Nz;n++){
        float f=0.f, bb=0.f;
        for (int m=0;m<Nz;m++){ f = fmaf(s_L[n*Nz+m], s_wr[r*Nz+m], f); bb = fmaf(s_L[m*Nz+n], s_wr[r*Nz+m], bb); }
        s_fwd[r*Nz+n]=f; s_bwd[r*Nz+n]=bb;
      }
  }
  __syncthreads();

  // cosine(M_new, kr)   (waves 0..4 -> n, waves 5,6 -> ||kr||^2)
  if (wv < Nz){
    const int n = wv;
    float pm=0.f,p0=0.f,p1=0.f;
    for (int w=ln; w<Wz; w+=64){
      float mv=s_M[n*Wz+w];
      pm=fmaf(mv,mv,pm);
      p0=fmaf(s_xi[O_KR+w],    mv,p0);
      p1=fmaf(s_xi[O_KR+Wz+w], mv,p1);
    }
    for (int off=32; off; off>>=1){
      pm += __shfl_down(pm,off,64); p0 += __shfl_down(p0,off,64); p1 += __shfl_down(p1,off,64);
    }
    if (ln==0){ s_m2[n]=pm; s_d0[n]=p0; s_d1[n]=p1; }
  } else if (wv == 5 || wv == 6){
    const int r = wv - 5;
    float p2=0.f;
    for (int w=ln; w<Wz; w+=64){ float kv=s_xi[O_KR+r*Wz+w]; p2=fmaf(kv,kv,p2); }
    for (int off=32; off; off>>=1) p2 += __shfl_down(p2,off,64);
    if (ln==0) s_kr2[r]=p2;
  }
  __syncthreads();

  if (tid == 0){
    for (int r=0;r<Rz;r++){
      float rk = rsqrtf(s_kr2[r]+EPSF);
      const float* dd = (r==0) ? s_d0 : s_d1;
      float br = s_sc[r];
      float lg[Nz], mx=-1e30f;
      for (int n=0;n<Nz;n++){ lg[n] = br*dd[n]*rk*rsqrtf(s_m2[n]+EPSF); mx=fmaxf(mx,lg[n]); }
      float ssum=0.f;
      for (int n=0;n<Nz;n++){ lg[n]=expf(lg[n]-mx); ssum+=lg[n]; }
      for (int n=0;n<Nz;n++){
        float crn = lg[n]/ssum;
        s_wr[r*Nz+n] = s_sc[7+r*3+0]*s_bwd[r*Nz+n] + s_sc[7+r*3+1]*crn + s_sc[7+r*3+2]*s_fwd[r*Nz+n];
      }
    }
  }
  __syncthreads();

  // read vectors + state writeback   (rT layout: [2][b][RW])
  float* rdst = rT + (size_t)((t+1)&1)*RWz*Bz + (size_t)b*RWz;
  for (int w = tid; w < Wz; w += NT){
    float m0=s_M[0*Wz+w], m1=s_M[1*Wz+w], m2=s_M[2*Wz+w], m3=s_M[3*Wz+w], m4=s_M[4*Wz+w];
    for (int r=0;r<Rz;r++){
      float rv = s_wr[r*Nz+0]*m0 + s_wr[r*Nz+1]*m1 + s_wr[r*Nz+2]*m2
               + s_wr[r*Nz+3]*m3 + s_wr[r*Nz+4]*m4;
      rdst[r*Wz + w] = rv;
    }
  }
  for (int i = tid; i < Nz*Wz; i += NT) Mg[(size_t)b*Nz*Wz+i] = s_M[i];
  if (tid < Nz){ ug[b*Nz+tid]=s_u[tid]; pg[b*Nz+tid]=s_p[tid]; wwg[b*Nz+tid]=s_ww[tid]; }
  if (tid < Nz*Nz) Lg[b*Nz*Nz+tid]=s_L[tid];
  if (tid < Rz*Nz) wrg[b*Rz*Nz+tid]=s_wr[tid];
}

__global__ void __launch_bounds__(NT, 4)
dnc_kernel(const int* __restrict__ src, const float* __restrict__ emb,
           const float* __restrict__ w_ih, const float* __restrict__ w_hh,
           const float* __restrict__ b_lstm,
           const float* __restrict__ w_xi, const float* __restrict__ b_xi,
           const float* __restrict__ w_out, const float* __restrict__ b_out,
           float* __restrict__ out, float* __restrict__ ws)
{
  cg::grid_group grid = cg::this_grid();
  const int tid = threadIdx.x;
  const int gid = blockIdx.x*NT + tid;

  // all per-batch tensors are [b][feature] (contiguous per-row -> float4)
  float* embT  = ws;                                   // [T][B][H]
  float* wxiT  = embT  + (size_t)Tz*Hz*Bz;             // [IF][H]
  float* woutT = wxiT  + (size_t)IFz*Hz;               // [H][XD]
  float* hT    = woutT + (size_t)Hz*XD;                // [2][B][H]
  float* cT    = hT    + 2*Hz*Bz;                      // [B][H]
  float* rT    = cT    + Hz*Bz;                        // [2][B][RW]
  float* xiT   = rT    + 2*RWz*Bz;                     // [B][IF]
  float* Mg    = xiT   + (size_t)IFz*Bz;               // [B][N][W]
  float* ug    = Mg    + (size_t)Bz*Nz*Wz;             // [B][N]
  float* pg    = ug    + Bz*Nz;
  float* wwg   = pg    + Bz*Nz;
  float* Lg    = wwg   + Bz*Nz;                        // [B][N*N]
  float* wrg   = Lg    + Bz*Nz*Nz;                     // [B][R*N]

  // ---- phase 0: init / transposes / embedding gather ----
  for (size_t i = gid; i < (size_t)Tz*Hz*Bz; i += NTH){
    int k = (int)(i & 511); int b = (int)((i >> 9) & 31); int t = (int)(i >> 14);
    embT[i] = emb[(size_t)src[b*Tz + t]*Hz + k];
  }
  for (size_t i = gid; i < (size_t)IFz*Hz; i += NTH){
    int k = (int)(i % Hz); size_t f = i / Hz;
    wxiT[i] = w_xi[(size_t)k*IFz + f];
  }
  for (size_t i = gid; i < (size_t)Hz*XD; i += NTH){
    int k = (int)(i % XD); int j = (int)(i / XD);
    woutT[i] = w_out[(size_t)k*Hz + j];
  }
  for (int i = gid; i < 2*Hz*Bz; i += NTH) hT[i]=0.f;
  for (int i = gid; i < Hz*Bz;   i += NTH) cT[i]=0.f;
  for (int i = gid; i < 2*RWz*Bz;i += NTH) rT[i]=0.f;
  for (int i = gid; i < Bz*Nz*Wz;i += NTH) Mg[i]=0.f;
  for (int i = gid; i < Bz*(3*Nz + Nz*Nz + Rz*Nz); i += NTH) ug[i]=0.f; // ug..wrg contiguous
  grid.sync();

  // ---- time loop ----
  for (int t = 0; t < Tz; ++t){
    const int cur = t & 1, nxt = (t+1)&1;

    // Phase A: gates GEMM (4-way K-split per output) + LSTM pointwise
    // o = gid>>2 in [0,65536): gate=o&3, b=(o>>2)&31, j=o>>7 ; ks = gid&3
    {
      const int ks   = gid & 3;
      const int o    = gid >> 2;
      const int gate = o & 3;
      const int b    = (o >> 2) & 31;
      const int j    = o >> 7;
      const int row  = gate*Hz + j;
      const float* xp; const float* wp;
      if (ks == 0){ xp = embT + ((size_t)t*Bz + b)*Hz;                 wp = w_ih + (size_t)row*XD; }
      else if (ks == 1){ xp = rT + (size_t)cur*RWz*Bz + (size_t)b*RWz;      wp = w_ih + (size_t)row*XD + Hz; }
      else if (ks == 2){ xp = rT + (size_t)cur*RWz*Bz + (size_t)b*RWz + Hz; wp = w_ih + (size_t)row*XD + 2*Hz; }
      else { xp = hT + (size_t)cur*Hz*Bz + (size_t)b*Hz;               wp = w_hh + (size_t)row*Hz; }
      float acc = dot4(xp, wp, Hz);
      acc += __shfl_xor(acc, 1, 64);
      acc += __shfl_xor(acc, 2, 64);
      acc += b_lstm[row];
      // lane = gate*4 + (b&3)*16 + ks ; gather the 4 gates for this b
      const int lane = tid & 63;
      const int base = lane & 48;
      float gi = __shfl(acc, base+0,  64);
      float gf = __shfl(acc, base+4,  64);
      float gg = __shfl(acc, base+8,  64);
      float go = __shfl(acc, base+12, 64);
      if ((lane & 15) == 0){   // gate==0 && ks==0
        float cv = cT[(size_t)b*Hz + j];
        float cn = sigf(gf)*cv + sigf(gi)*tanhf(gg);
        float hn = sigf(go)*tanhf(cn);
        cT[(size_t)b*Hz + j] = cn;
        hT[(size_t)nxt*Hz*Bz + (size_t)b*Hz + j] = hn;
      }
    }
    grid.sync();

    // Phase B: xi = h_new @ w_xi + b_xi   (2-way K-split)
    {
      const float* hbase = hT + (size_t)nxt*Hz*Bz;
      const int o  = gid >> 1;
      const int ks = gid & 1;
      if (o < Bz*IFz){
        const int b = o / IFz;
        const int f = o - b*IFz;
        float acc = dot4(hbase + (size_t)b*Hz + ks*256, wxiT + (size_t)f*Hz + ks*256, 256);
        acc += __shfl_xor(acc, 1, 64);
        if (ks == 0) xiT[o] = acc + b_xi[f];
      }
    }
    grid.sync();

    // Phase C: WGs 0..31 do DNC memory ops; WGs 32+ compute out(t-1)
    if (blockIdx.x < Bz){
      memops(blockIdx.x, t, xiT, Mg, ug, pg, wwg, Lg, wrg, rT);
    } else if (t > 0){
      const int id = (blockIdx.x - Bz)*NT + tid;
      if (id < Hz*Bz*4){
        const int ks = id & 3;
        const int o  = id >> 2;
        const int b  = o & 31;
        const int j  = o >> 5;
        const float* wj = woutT + (size_t)j*XD;
        float acc;
        if (ks == 0)      acc = dot4(hT + (size_t)cur*Hz*Bz  + (size_t)b*Hz,        wj,        Hz);
        else if (ks == 1) acc = dot4(rT + (size_t)cur*RWz*Bz + (size_t)b*RWz,       wj + Hz,   Hz);
        else if (ks == 2) acc = dot4(rT + (size_t)cur*RWz*Bz + (size_t)b*RWz + Hz,  wj + 2*Hz, Hz);
        else              acc = 0.f;
        acc += __shfl_xor(acc, 1, 64);
        acc += __shfl_xor(acc, 2, 64);
        if (ks == 0)
          out[(size_t)b*Tz*Hz + (size_t)(t-1)*Hz + j] = acc + b_out[j];
      }
    }
    grid.sync();
  }

  // ---- epilogue: out(T-1), final h and c ----
  if (gid < Hz*Bz){
    const int b = gid & 31, j = gid >> 5;
    const float* wj = woutT + (size_t)j*XD;
    float acc = dot4(hT + (size_t)b*Hz,  wj,      Hz)     // h(256) in hT[0]
              + dot4(rT + (size_t)b*RWz, wj + Hz, RWz)    // r(256) in rT[0]
              + b_out[j];
    out[(size_t)b*Tz*Hz + (size_t)(Tz-1)*Hz + j] = acc;
    out[(size_t)Bz*Tz*Hz + (size_t)b*Hz + j]                 = hT[(size_t)b*Hz + j];
    out[(size_t)Bz*Tz*Hz + (size_t)Bz*Hz + (size_t)b*Hz + j] = cT[(size_t)b*Hz + j];
  }
}

extern "C" void kernel_launch(void* const* d_in, const int* in_sizes, int n_in,
                              void* d_out, int out_size, void* d_ws, size_t ws_size,
                              hipStream_t stream)
{
  const int*   src    = (const int*)  d_in[0];
  // d_in[1] = source_lengths (unused by reference)
  const float* emb    = (const float*)d_in[2];
  const float* w_ih   = (const float*)d_in[3];
  const float* w_hh   = (const float*)d_in[4];
  const float* b_lstm = (const float*)d_in[5];
  const float* w_xi   = (const float*)d_in[6];
  const float* b_xi   = (const float*)d_in[7];
  const float* w_out  = (const float*)d_in[8];
  const float* b_out  = (const float*)d_in[9];
  float* out = (float*)d_out;
  float* ws  = (float*)d_ws;

  void* args[] = { &src, &emb, &w_ih, &w_hh, &b_lstm, &w_xi, &b_xi, &w_out, &b_out, &out, &ws };
  hipLaunchCooperativeKernel((const void*)dnc_kernel, dim3(NWG), dim3(NT), args, 0, stream);
}

// Round 3
// 85324.182 us; speedup vs baseline: 1.0189x; 1.0189x over previous
//
#include <hip/hip_runtime.h>
#include <hip/hip_cooperative_groups.h>

namespace cg = cooperative_groups;

#define Bz 32
#define Tz 256
#define Hz 512
#define Nz 5
#define Rz 2
#define Wz 512
#define RWz 1024
#define XD 1536          // H + R*W
#define IFz 2573         // R*W + 3*W + 5*R + 3
#define EPSF 1e-6f
#define NWG 256
#define NT 1024
#define NTH (NWG*NT)     // 262144

// xi field offsets
#define O_KR 0
#define O_BR 1024
#define O_KW 1026
#define O_BW 1538
#define O_E  1539
#define O_V  2051
#define O_FG 2563
#define O_GA 2565
#define O_GW 2566
#define O_PI 2567

__device__ __forceinline__ float sigf(float x){ return 1.0f/(1.0f+expf(-x)); }
__device__ __forceinline__ float splus(float x){ return fmaxf(x,0.0f) + log1pf(expf(-fabsf(x))); }

// contiguous-x · contiguous-w dot, float4 both sides, n % 16 == 0
__device__ __forceinline__ float dot4(const float* __restrict__ x,
                                      const float* __restrict__ w, int n){
  const float4* x4 = (const float4*)x;
  const float4* w4 = (const float4*)w;
  float a0=0.f,a1=0.f,a2=0.f,a3=0.f;
  #pragma unroll 4
  for (int k=0;k<n/4;k++){
    float4 xv = x4[k], wv = w4[k];
    a0 = fmaf(xv.x,wv.x,a0); a1 = fmaf(xv.y,wv.y,a1);
    a2 = fmaf(xv.z,wv.z,a2); a3 = fmaf(xv.w,wv.w,a3);
  }
  return (a0+a1)+(a2+a3);
}

__device__ void memops(int b, int t, const float* xiT,
                       float* Mg, float* ug, float* pg, float* wwg, float* Lg, float* wrg,
                       float* rT)
{
  __shared__ float s_xi[IFz];
  __shared__ float s_M[Nz*Wz];
  __shared__ float s_u[Nz], s_p[Nz], s_ww[Nz], s_a[Nz], s_L[Nz*Nz], s_wr[Rz*Nz];
  __shared__ float s_sc[13]; // 0:br0 1:br1 2:bw 3:fg0 4:fg1 5:ga 6:gw 7..12:pi
  __shared__ float s_m2[Nz], s_dt[Nz], s_d0[Nz], s_d1[Nz];
  __shared__ float s_kw2, s_kr2[2];
  __shared__ float s_fwd[Rz*Nz], s_bwd[Rz*Nz];

  const int tid = threadIdx.x;
  const int wv = tid >> 6, ln = tid & 63;

  for (int f = tid; f < IFz; f += NT) s_xi[f] = xiT[(size_t)b*IFz + f];
  for (int i = tid; i < Nz*Wz; i += NT) s_M[i] = Mg[(size_t)b*Nz*Wz + i];
  if (tid < Nz){ s_u[tid]=ug[b*Nz+tid]; s_p[tid]=pg[b*Nz+tid]; s_ww[tid]=wwg[b*Nz+tid]; }
  if (tid < Nz*Nz) s_L[tid] = Lg[b*Nz*Nz+tid];
  if (tid < Rz*Nz) s_wr[tid] = wrg[b*Rz*Nz+tid];
  __syncthreads();

  if (tid == 0){
    s_sc[0] = 1.0f + splus(s_xi[O_BR+0]);
    s_sc[1] = 1.0f + splus(s_xi[O_BR+1]);
    s_sc[2] = 1.0f + splus(s_xi[O_BW]);
    s_sc[3] = sigf(s_xi[O_FG+0]);
    s_sc[4] = sigf(s_xi[O_FG+1]);
    s_sc[5] = sigf(s_xi[O_GA]);
    s_sc[6] = sigf(s_xi[O_GW]);
    for (int r=0;r<Rz;r++){
      float x0=s_xi[O_PI+r*3+0], x1=s_xi[O_PI+r*3+1], x2=s_xi[O_PI+r*3+2];
      float m = fmaxf(x0,fmaxf(x1,x2));
      float e0=expf(x0-m), e1=expf(x1-m), e2=expf(x2-m);
      float s = e0+e1+e2;
      s_sc[7+r*3+0]=e0/s; s_sc[7+r*3+1]=e1/s; s_sc[7+r*3+2]=e2/s;
    }
  }
  __syncthreads();

  // psi & usage update (uses OLD ww, OLD wr)
  if (tid < Nz){
    float psi = (1.0f - s_sc[3]*s_wr[0*Nz+tid]) * (1.0f - s_sc[4]*s_wr[1*Nz+tid]);
    float uu = s_u[tid], w = s_ww[tid];
    s_u[tid] = (uu + w - uu*w) * psi;
  }

  // cosine(M_old, kw): per-wave fused dot + ||M_n||^2  (waves 0..4 -> n, wave 5 -> ||kw||^2)
  if (wv < Nz){
    const int n = wv;
    float pd=0.f, pm=0.f;
    for (int w = ln; w < Wz; w += 64){
      float kv = s_xi[O_KW+w], mv = s_M[n*Wz+w];
      pd = fmaf(kv,mv,pd); pm = fmaf(mv,mv,pm);
    }
    for (int off=32; off; off>>=1){ pd += __shfl_down(pd,off,64); pm += __shfl_down(pm,off,64); }
    if (ln==0){ s_dt[n]=pd; s_m2[n]=pm; }
  } else if (wv == 5){
    float p2=0.f;
    for (int w=ln; w<Wz; w+=64){ float kv=s_xi[O_KW+w]; p2=fmaf(kv,kv,p2); }
    for (int off=32; off; off>>=1) p2 += __shfl_down(p2,off,64);
    if (ln==0) s_kw2 = p2;
  }
  __syncthreads();

  if (tid == 0){
    // allocation weights from updated u (stable ascending argsort, N=5)
    float su[Nz]; int idx[Nz];
    for (int i=0;i<Nz;i++){
      float v = EPSF + (1.0f-EPSF)*s_u[i];
      int j=i;
      while (j>0 && su[j-1] > v){ su[j]=su[j-1]; idx[j]=idx[j-1]; j--; }
      su[j]=v; idx[j]=i;
    }
    float cp = 1.0f;
    for (int k=0;k<Nz;k++){ s_a[idx[k]] = (1.0f - su[k])*cp; cp *= su[k]; }
    // content write weights
    float rk = rsqrtf(s_kw2 + EPSF);
    float lg[Nz], mx=-1e30f;
    for (int n=0;n<Nz;n++){ lg[n] = s_sc[2]*s_dt[n]*rk*rsqrtf(s_m2[n]+EPSF); mx=fmaxf(mx,lg[n]); }
    float ssum=0.f;
    for (int n=0;n<Nz;n++){ lg[n]=expf(lg[n]-mx); ssum+=lg[n]; }
    float ga=s_sc[5], gw=s_sc[6];
    for (int n=0;n<Nz;n++){ float cwn = lg[n]/ssum; s_ww[n] = gw*(ga*s_a[n] + (1.0f-ga)*cwn); }
  }
  __syncthreads();

  // memory write
  for (int i = tid; i < Nz*Wz; i += NT){
    int n = i >> 9, w = i & 511;
    float e = sigf(s_xi[O_E+w]);
    float v = s_xi[O_V+w];
    s_M[i] = s_M[i]*(1.0f - s_ww[n]*e) + s_ww[n]*v;
  }
  __syncthreads();

  // link matrix, precedence, fwd/bwd (tiny, serial)
  if (tid == 0){
    float wsum = 0.f;
    for (int n=0;n<Nz;n++) wsum += s_ww[n];
    float Lo[Nz*Nz];
    for (int i=0;i<Nz;i++)
      for (int j=0;j<Nz;j++)
        Lo[i*Nz+j] = (i==j) ? 0.0f : ((1.0f - s_ww[i] - s_ww[j])*s_L[i*Nz+j] + s_ww[i]*s_p[j]);
    for (int i=0;i<Nz*Nz;i++) s_L[i]=Lo[i];
    for (int j=0;j<Nz;j++) s_p[j] = (1.0f-wsum)*s_p[j] + s_ww[j];
    for (int r=0;r<Rz;r++)
      for (int n=0;n<Nz;n++){
        float f=0.f, bb=0.f;
        for (int m=0;m<Nz;m++){ f = fmaf(s_L[n*Nz+m], s_wr[r*Nz+m], f); bb = fmaf(s_L[m*Nz+n], s_wr[r*Nz+m], bb); }
        s_fwd[r*Nz+n]=f; s_bwd[r*Nz+n]=bb;
      }
  }
  __syncthreads();

  // cosine(M_new, kr)   (waves 0..4 -> n, waves 5,6 -> ||kr||^2)
  if (wv < Nz){
    const int n = wv;
    float pm=0.f,p0=0.f,p1=0.f;
    for (int w=ln; w<Wz; w+=64){
      float mv=s_M[n*Wz+w];
      pm=fmaf(mv,mv,pm);
      p0=fmaf(s_xi[O_KR+w],    mv,p0);
      p1=fmaf(s_xi[O_KR+Wz+w], mv,p1);
    }
    for (int off=32; off; off>>=1){
      pm += __shfl_down(pm,off,64); p0 += __shfl_down(p0,off,64); p1 += __shfl_down(p1,off,64);
    }
    if (ln==0){ s_m2[n]=pm; s_d0[n]=p0; s_d1[n]=p1; }
  } else if (wv == 5 || wv == 6){
    const int r = wv - 5;
    float p2=0.f;
    for (int w=ln; w<Wz; w+=64){ float kv=s_xi[O_KR+r*Wz+w]; p2=fmaf(kv,kv,p2); }
    for (int off=32; off; off>>=1) p2 += __shfl_down(p2,off,64);
    if (ln==0) s_kr2[r]=p2;
  }
  __syncthreads();

  if (tid == 0){
    for (int r=0;r<Rz;r++){
      float rk = rsqrtf(s_kr2[r]+EPSF);
      const float* dd = (r==0) ? s_d0 : s_d1;
      float br = s_sc[r];
      float lg[Nz], mx=-1e30f;
      for (int n=0;n<Nz;n++){ lg[n] = br*dd[n]*rk*rsqrtf(s_m2[n]+EPSF); mx=fmaxf(mx,lg[n]); }
      float ssum=0.f;
      for (int n=0;n<Nz;n++){ lg[n]=expf(lg[n]-mx); ssum+=lg[n]; }
      for (int n=0;n<Nz;n++){
        float crn = lg[n]/ssum;
        s_wr[r*Nz+n] = s_sc[7+r*3+0]*s_bwd[r*Nz+n] + s_sc[7+r*3+1]*crn + s_sc[7+r*3+2]*s_fwd[r*Nz+n];
      }
    }
  }
  __syncthreads();

  // read vectors + state writeback   (rT layout: [2][b][RW])
  float* rdst = rT + (size_t)((t+1)&1)*RWz*Bz + (size_t)b*RWz;
  for (int w = tid; w < Wz; w += NT){
    float m0=s_M[0*Wz+w], m1=s_M[1*Wz+w], m2=s_M[2*Wz+w], m3=s_M[3*Wz+w], m4=s_M[4*Wz+w];
    for (int r=0;r<Rz;r++){
      float rv = s_wr[r*Nz+0]*m0 + s_wr[r*Nz+1]*m1 + s_wr[r*Nz+2]*m2
               + s_wr[r*Nz+3]*m3 + s_wr[r*Nz+4]*m4;
      rdst[r*Wz + w] = rv;
    }
  }
  for (int i = tid; i < Nz*Wz; i += NT) Mg[(size_t)b*Nz*Wz+i] = s_M[i];
  if (tid < Nz){ ug[b*Nz+tid]=s_u[tid]; pg[b*Nz+tid]=s_p[tid]; wwg[b*Nz+tid]=s_ww[tid]; }
  if (tid < Nz*Nz) Lg[b*Nz*Nz+tid]=s_L[tid];
  if (tid < Rz*Nz) wrg[b*Rz*Nz+tid]=s_wr[tid];
}

__global__ void __launch_bounds__(NT, 4)
dnc_kernel(const int* __restrict__ src, const float* __restrict__ emb,
           const float* __restrict__ w_ih, const float* __restrict__ w_hh,
           const float* __restrict__ b_lstm,
           const float* __restrict__ w_xi, const float* __restrict__ b_xi,
           const float* __restrict__ w_out, const float* __restrict__ b_out,
           float* __restrict__ out, float* __restrict__ ws)
{
  cg::grid_group grid = cg::this_grid();
  const int tid = threadIdx.x;
  const int gid = blockIdx.x*NT + tid;

  // all per-batch tensors are [b][feature] (contiguous per-row -> float4)
  float* embT  = ws;                                   // [T][B][H]
  float* wxiT  = embT  + (size_t)Tz*Hz*Bz;             // [IF][H]
  float* woutT = wxiT  + (size_t)IFz*Hz;               // [H][XD]
  float* hT    = woutT + (size_t)Hz*XD;                // [2][B][H]
  float* cT    = hT    + 2*Hz*Bz;                      // [B][H]
  float* rT    = cT    + Hz*Bz;                        // [2][B][RW]
  float* xiT   = rT    + 2*RWz*Bz;                     // [B][IF]
  float* Mg    = xiT   + (size_t)IFz*Bz;               // [B][N][W]
  float* ug    = Mg    + (size_t)Bz*Nz*Wz;             // [B][N]
  float* pg    = ug    + Bz*Nz;
  float* wwg   = pg    + Bz*Nz;
  float* Lg    = wwg   + Bz*Nz;                        // [B][N*N]
  float* wrg   = Lg    + Bz*Nz*Nz;                     // [B][R*N]

  // ---- phase 0: init / transposes / embedding gather ----
  for (size_t i = gid; i < (size_t)Tz*Hz*Bz; i += NTH){
    int k = (int)(i & 511); int b = (int)((i >> 9) & 31); int t = (int)(i >> 14);
    embT[i] = emb[(size_t)src[b*Tz + t]*Hz + k];
  }
  for (size_t i = gid; i < (size_t)IFz*Hz; i += NTH){
    int k = (int)(i % Hz); size_t f = i / Hz;
    wxiT[i] = w_xi[(size_t)k*IFz + f];
  }
  for (size_t i = gid; i < (size_t)Hz*XD; i += NTH){
    int k = (int)(i % XD); int j = (int)(i / XD);
    woutT[i] = w_out[(size_t)k*Hz + j];
  }
  for (int i = gid; i < 2*Hz*Bz; i += NTH) hT[i]=0.f;
  for (int i = gid; i < Hz*Bz;   i += NTH) cT[i]=0.f;
  for (int i = gid; i < 2*RWz*Bz;i += NTH) rT[i]=0.f;
  for (int i = gid; i < Bz*Nz*Wz;i += NTH) Mg[i]=0.f;
  for (int i = gid; i < Bz*(3*Nz + Nz*Nz + Rz*Nz); i += NTH) ug[i]=0.f; // ug..wrg contiguous
  grid.sync();

  // ---- time loop ----
  for (int t = 0; t < Tz; ++t){
    const int cur = t & 1, nxt = (t+1)&1;

    // Phase A: gates GEMM (4-way K-split per output) + LSTM pointwise
    // o = gid>>2 in [0,65536): gate=o&3, b=(o>>2)&31, j=o>>7 ; ks = gid&3
    // row pinning: WG blk owns j in {2blk, 2blk+1} every step -> 64KB/WG L2-resident
    {
      const int ks   = gid & 3;
      const int o    = gid >> 2;
      const int gate = o & 3;
      const int b    = (o >> 2) & 31;
      const int j    = o >> 7;
      const int row  = gate*Hz + j;
      const float* xp; const float* wp;
      if (ks == 0){ xp = embT + ((size_t)t*Bz + b)*Hz;                 wp = w_ih + (size_t)row*XD; }
      else if (ks == 1){ xp = rT + (size_t)cur*RWz*Bz + (size_t)b*RWz;      wp = w_ih + (size_t)row*XD + Hz; }
      else if (ks == 2){ xp = rT + (size_t)cur*RWz*Bz + (size_t)b*RWz + Hz; wp = w_ih + (size_t)row*XD + 2*Hz; }
      else { xp = hT + (size_t)cur*Hz*Bz + (size_t)b*Hz;               wp = w_hh + (size_t)row*Hz; }
      float acc = dot4(xp, wp, Hz);
      acc += __shfl_xor(acc, 1, 64);
      acc += __shfl_xor(acc, 2, 64);
      acc += b_lstm[row];
      // lane = gate*4 + (b&3)*16 + ks ; gather the 4 gates for this b
      const int lane = tid & 63;
      const int base = lane & 48;
      float gi = __shfl(acc, base+0,  64);
      float gf = __shfl(acc, base+4,  64);
      float gg = __shfl(acc, base+8,  64);
      float go = __shfl(acc, base+12, 64);
      if ((lane & 15) == 0){   // gate==0 && ks==0
        float cv = cT[(size_t)b*Hz + j];
        float cn = sigf(gf)*cv + sigf(gi)*tanhf(gg);
        float hn = sigf(go)*tanhf(cn);
        cT[(size_t)b*Hz + j] = cn;
        hT[(size_t)nxt*Hz*Bz + (size_t)b*Hz + j] = hn;
      }
    }
    grid.sync();

    // Phase B: xi = h_new @ w_xi + b_xi   (2-way K-split, wave-per-feature-row)
    // lane = ks(2) x b(32); one wave owns one f row -> weight chunk broadcast to 32 lanes.
    // WG blk owns f in [16*blk, 16*blk+16) every step -> 32KB/WG L2-resident.
    {
      const float* hbase = hT + (size_t)nxt*Hz*Bz;
      const int ks = gid & 1;
      const int b  = (gid >> 1) & 31;
      const int f  = gid >> 6;
      if (f < IFz){
        float acc = dot4(hbase + (size_t)b*Hz + ks*256, wxiT + (size_t)f*Hz + ks*256, 256);
        acc += __shfl_xor(acc, 1, 64);
        if (ks == 0) xiT[(size_t)b*IFz + f] = acc + b_xi[f];
      }
    }
    grid.sync();

    // Phase C: WGs 0..31 do DNC memory ops; WGs 32+ compute out(t-1)
    if (blockIdx.x < Bz){
      memops(blockIdx.x, t, xiT, Mg, ug, pg, wwg, Lg, wrg, rT);
    } else if (t > 0){
      const int id = (blockIdx.x - Bz)*NT + tid;
      if (id < Hz*Bz*4){
        const int ks = id & 3;
        const int o  = id >> 2;
        const int b  = o & 31;
        const int j  = o >> 5;
        const float* wj = woutT + (size_t)j*XD;
        float acc;
        if (ks == 0)      acc = dot4(hT + (size_t)cur*Hz*Bz  + (size_t)b*Hz,        wj,        Hz);
        else if (ks == 1) acc = dot4(rT + (size_t)cur*RWz*Bz + (size_t)b*RWz,       wj + Hz,   Hz);
        else if (ks == 2) acc = dot4(rT + (size_t)cur*RWz*Bz + (size_t)b*RWz + Hz,  wj + 2*Hz, Hz);
        else              acc = 0.f;
        acc += __shfl_xor(acc, 1, 64);
        acc += __shfl_xor(acc, 2, 64);
        if (ks == 0)
          out[(size_t)b*Tz*Hz + (size_t)(t-1)*Hz + j] = acc + b_out[j];
      }
    }
    grid.sync();
  }

  // ---- epilogue: out(T-1), final h and c ----
  if (gid < Hz*Bz){
    const int b = gid & 31, j = gid >> 5;
    const float* wj = woutT + (size_t)j*XD;
    float acc = dot4(hT + (size_t)b*Hz,  wj,      Hz)     // h(final) in hT[0]
              + dot4(rT + (size_t)b*RWz, wj + Hz, RWz)    // r(final) in rT[0]
              + b_out[j];
    out[(size_t)b*Tz*Hz + (size_t)(Tz-1)*Hz + j] = acc;
    out[(size_t)Bz*Tz*Hz + (size_t)b*Hz + j]                 = hT[(size_t)b*Hz + j];
    out[(size_t)Bz*Tz*Hz + (size_t)Bz*Hz + (size_t)b*Hz + j] = cT[(size_t)b*Hz + j];
  }
}

extern "C" void kernel_launch(void* const* d_in, const int* in_sizes, int n_in,
                              void* d_out, int out_size, void* d_ws, size_t ws_size,
                              hipStream_t stream)
{
  const int*   src    = (const int*)  d_in[0];
  // d_in[1] = source_lengths (unused by reference)
  const float* emb    = (const float*)d_in[2];
  const float* w_ih   = (const float*)d_in[3];
  const float* w_hh   = (const float*)d_in[4];
  const float* b_lstm = (const float*)d_in[5];
  const float* w_xi   = (const float*)d_in[6];
  const float* b_xi   = (const float*)d_in[7];
  const float* w_out  = (const float*)d_in[8];
  const float* b_out  = (const float*)d_in[9];
  float* out = (float*)d_out;
  float* ws  = (float*)d_ws;

  void* args[] = { &src, &emb, &w_ih, &w_hh, &b_lstm, &w_xi, &b_xi, &w_out, &b_out, &out, &ws };
  hipLaunchCooperativeKernel((const void*)dnc_kernel, dim3(NWG), dim3(NT), args, 0, stream);
}

// Round 4
// 52691.089 us; speedup vs baseline: 1.6499x; 1.6193x over previous
//
#include <hip/hip_runtime.h>
#include <hip/hip_cooperative_groups.h>

namespace cg = cooperative_groups;

#define Bz 32
#define Tz 256
#define Hz 512
#define Nz 5
#define Rz 2
#define Wz 512
#define RWz 1024
#define XD 1536          // H + R*W
#define IFz 2573         // R*W + 3*W + 5*R + 3
#define EPSF 1e-6f
#define NWG 256
#define NT 256
#define NTH (NWG*NT)     // 65536

// interleaved state layout: [kg][b][4] where feature index i -> kg=i>>2, kk=i&3
// slab stride per kg = 32*4 = 128 floats
#define HSLAB 16384      // 128 kg * 128
#define RSLAB 32768      // 256 kg * 128

// xi field offsets
#define O_KR 0
#define O_BR 1024
#define O_KW 1026
#define O_BW 1538
#define O_E  1539
#define O_V  2051
#define O_FG 2563
#define O_GA 2565
#define O_GW 2566
#define O_PI 2567

__device__ __forceinline__ float sigf(float x){ return 1.0f/(1.0f+expf(-x)); }
__device__ __forceinline__ float splus(float x){ return fmaxf(x,0.0f) + log1pf(expf(-fabsf(x))); }

// x: interleaved state, pre-offset by b*4; walks kg slabs (stride 128 floats)
// w: contiguous row. nkg = number of float4 groups (multiple of 8).
__device__ __forceinline__ float dotI(const float* __restrict__ x,
                                      const float* __restrict__ w, int nkg){
  const float4* w4 = (const float4*)w;
  float a0=0.f,a1=0.f,a2=0.f,a3=0.f;
  #pragma unroll 8
  for (int kg=0; kg<nkg; kg++){
    float4 xv = *(const float4*)(x + (size_t)kg*128);
    float4 wv = w4[kg];
    a0 = fmaf(xv.x,wv.x,a0); a1 = fmaf(xv.y,wv.y,a1);
    a2 = fmaf(xv.z,wv.z,a2); a3 = fmaf(xv.w,wv.w,a3);
  }
  return (a0+a1)+(a2+a3);
}

__device__ void memops(int b, int t, const float* xiT,
                       float* Mg, float* ug, float* pg, float* wwg, float* Lg, float* wrg,
                       float* rT)
{
  __shared__ float s_xi[IFz];
  __shared__ float s_M[Nz*Wz];
  __shared__ float s_u[Nz], s_p[Nz], s_ww[Nz], s_a[Nz], s_L[Nz*Nz], s_wr[Rz*Nz];
  __shared__ float s_sc[13]; // 0:br0 1:br1 2:bw 3:fg0 4:fg1 5:ga 6:gw 7..12:pi
  __shared__ float s_m2[Nz], s_dt[Nz], s_d0[Nz], s_d1[Nz];
  __shared__ float s_kw2, s_kr2[2];
  __shared__ float s_fwd[Rz*Nz], s_bwd[Rz*Nz];

  const int tid = threadIdx.x;
  const int wv = tid >> 6, ln = tid & 63;

  for (int f = tid; f < IFz; f += NT) s_xi[f] = xiT[(size_t)b*IFz + f];
  for (int i = tid; i < Nz*Wz; i += NT) s_M[i] = Mg[(size_t)b*Nz*Wz + i];
  if (tid < Nz){ s_u[tid]=ug[b*Nz+tid]; s_p[tid]=pg[b*Nz+tid]; s_ww[tid]=wwg[b*Nz+tid]; }
  if (tid < Nz*Nz) s_L[tid] = Lg[b*Nz*Nz+tid];
  if (tid < Rz*Nz) s_wr[tid] = wrg[b*Rz*Nz+tid];
  __syncthreads();

  if (tid == 0){
    s_sc[0] = 1.0f + splus(s_xi[O_BR+0]);
    s_sc[1] = 1.0f + splus(s_xi[O_BR+1]);
    s_sc[2] = 1.0f + splus(s_xi[O_BW]);
    s_sc[3] = sigf(s_xi[O_FG+0]);
    s_sc[4] = sigf(s_xi[O_FG+1]);
    s_sc[5] = sigf(s_xi[O_GA]);
    s_sc[6] = sigf(s_xi[O_GW]);
    for (int r=0;r<Rz;r++){
      float x0=s_xi[O_PI+r*3+0], x1=s_xi[O_PI+r*3+1], x2=s_xi[O_PI+r*3+2];
      float m = fmaxf(x0,fmaxf(x1,x2));
      float e0=expf(x0-m), e1=expf(x1-m), e2=expf(x2-m);
      float s = e0+e1+e2;
      s_sc[7+r*3+0]=e0/s; s_sc[7+r*3+1]=e1/s; s_sc[7+r*3+2]=e2/s;
    }
  }
  __syncthreads();

  // psi & usage update (uses OLD ww, OLD wr)
  if (tid < Nz){
    float psi = (1.0f - s_sc[3]*s_wr[0*Nz+tid]) * (1.0f - s_sc[4]*s_wr[1*Nz+tid]);
    float uu = s_u[tid], w = s_ww[tid];
    s_u[tid] = (uu + w - uu*w) * psi;
  }

  // cosine(M_old, kw)
  if (wv < Nz){
    const int n = wv;
    float pd=0.f, pm=0.f;
    for (int w = ln; w < Wz; w += 64){
      float kv = s_xi[O_KW+w], mv = s_M[n*Wz+w];
      pd = fmaf(kv,mv,pd); pm = fmaf(mv,mv,pm);
    }
    for (int off=32; off; off>>=1){ pd += __shfl_down(pd,off,64); pm += __shfl_down(pm,off,64); }
    if (ln==0){ s_dt[n]=pd; s_m2[n]=pm; }
  }
  { // ||kw||^2 on wave 3's spare? use a dedicated small path on wave 0 lanes? keep wave count: waves=4 (NT=256)
  }
  if (wv == 3){
    float p2=0.f;
    for (int w=ln; w<Wz; w+=64){ float kv=s_xi[O_KW+w]; p2=fmaf(kv,kv,p2); }
    for (int off=32; off; off>>=1) p2 += __shfl_down(p2,off,64);
    if (ln==0) s_kw2 = p2;
  }
  __syncthreads();
  // n=3 was skipped if wv==3 did kw2? No: wv<Nz covers 0..3 here (4 waves), n=4 missing -> handle n=4 on wave 0 second pass
  if (wv == 0){
    const int n = 4;
    float pd=0.f, pm=0.f;
    for (int w = ln; w < Wz; w += 64){
      float kv = s_xi[O_KW+w], mv = s_M[n*Wz+w];
      pd = fmaf(kv,mv,pd); pm = fmaf(mv,mv,pm);
    }
    for (int off=32; off; off>>=1){ pd += __shfl_down(pd,off,64); pm += __shfl_down(pm,off,64); }
    if (ln==0){ s_dt[n]=pd; s_m2[n]=pm; }
  }
  __syncthreads();

  if (tid == 0){
    // allocation weights from updated u (stable ascending argsort, N=5)
    float su[Nz]; int idx[Nz];
    for (int i=0;i<Nz;i++){
      float v = EPSF + (1.0f-EPSF)*s_u[i];
      int j=i;
      while (j>0 && su[j-1] > v){ su[j]=su[j-1]; idx[j]=idx[j-1]; j--; }
      su[j]=v; idx[j]=i;
    }
    float cp = 1.0f;
    for (int k=0;k<Nz;k++){ s_a[idx[k]] = (1.0f - su[k])*cp; cp *= su[k]; }
    // content write weights
    float rk = rsqrtf(s_kw2 + EPSF);
    float lg[Nz], mx=-1e30f;
    for (int n=0;n<Nz;n++){ lg[n] = s_sc[2]*s_dt[n]*rk*rsqrtf(s_m2[n]+EPSF); mx=fmaxf(mx,lg[n]); }
    float ssum=0.f;
    for (int n=0;n<Nz;n++){ lg[n]=expf(lg[n]-mx); ssum+=lg[n]; }
    float ga=s_sc[5], gw=s_sc[6];
    for (int n=0;n<Nz;n++){ float cwn = lg[n]/ssum; s_ww[n] = gw*(ga*s_a[n] + (1.0f-ga)*cwn); }
  }
  __syncthreads();

  // memory write
  for (int i = tid; i < Nz*Wz; i += NT){
    int n = i >> 9, w = i & 511;
    float e = sigf(s_xi[O_E+w]);
    float v = s_xi[O_V+w];
    s_M[i] = s_M[i]*(1.0f - s_ww[n]*e) + s_ww[n]*v;
  }
  __syncthreads();

  // link matrix, precedence, fwd/bwd
  if (tid == 0){
    float wsum = 0.f;
    for (int n=0;n<Nz;n++) wsum += s_ww[n];
    float Lo[Nz*Nz];
    for (int i=0;i<Nz;i++)
      for (int j=0;j<Nz;j++)
        Lo[i*Nz+j] = (i==j) ? 0.0f : ((1.0f - s_ww[i] - s_ww[j])*s_L[i*Nz+j] + s_ww[i]*s_p[j]);
    for (int i=0;i<Nz*Nz;i++) s_L[i]=Lo[i];
    for (int j=0;j<Nz;j++) s_p[j] = (1.0f-wsum)*s_p[j] + s_ww[j];
    for (int r=0;r<Rz;r++)
      for (int n=0;n<Nz;n++){
        float f=0.f, bb=0.f;
        for (int m=0;m<Nz;m++){ f = fmaf(s_L[n*Nz+m], s_wr[r*Nz+m], f); bb = fmaf(s_L[m*Nz+n], s_wr[r*Nz+m], bb); }
        s_fwd[r*Nz+n]=f; s_bwd[r*Nz+n]=bb;
      }
  }
  __syncthreads();

  // cosine(M_new, kr): waves 0..3 -> n 0..3 ; then wave0 n=4; waves 1,2 do ||kr||^2
  if (wv < 4){
    const int n = wv;
    float pm=0.f,p0=0.f,p1=0.f;
    for (int w=ln; w<Wz; w+=64){
      float mv=s_M[n*Wz+w];
      pm=fmaf(mv,mv,pm);
      p0=fmaf(s_xi[O_KR+w],    mv,p0);
      p1=fmaf(s_xi[O_KR+Wz+w], mv,p1);
    }
    for (int off=32; off; off>>=1){
      pm += __shfl_down(pm,off,64); p0 += __shfl_down(p0,off,64); p1 += __shfl_down(p1,off,64);
    }
    if (ln==0){ s_m2[n]=pm; s_d0[n]=p0; s_d1[n]=p1; }
  }
  __syncthreads();
  if (wv == 0){
    const int n = 4;
    float pm=0.f,p0=0.f,p1=0.f;
    for (int w=ln; w<Wz; w+=64){
      float mv=s_M[n*Wz+w];
      pm=fmaf(mv,mv,pm);
      p0=fmaf(s_xi[O_KR+w],    mv,p0);
      p1=fmaf(s_xi[O_KR+Wz+w], mv,p1);
    }
    for (int off=32; off; off>>=1){
      pm += __shfl_down(pm,off,64); p0 += __shfl_down(p0,off,64); p1 += __shfl_down(p1,off,64);
    }
    if (ln==0){ s_m2[n]=pm; s_d0[n]=p0; s_d1[n]=p1; }
  } else if (wv == 1 || wv == 2){
    const int r = wv - 1;
    float p2=0.f;
    for (int w=ln; w<Wz; w+=64){ float kv=s_xi[O_KR+r*Wz+w]; p2=fmaf(kv,kv,p2); }
    for (int off=32; off; off>>=1) p2 += __shfl_down(p2,off,64);
    if (ln==0) s_kr2[r]=p2;
  }
  __syncthreads();

  if (tid == 0){
    for (int r=0;r<Rz;r++){
      float rk = rsqrtf(s_kr2[r]+EPSF);
      const float* dd = (r==0) ? s_d0 : s_d1;
      float br = s_sc[r];
      float lg[Nz], mx=-1e30f;
      for (int n=0;n<Nz;n++){ lg[n] = br*dd[n]*rk*rsqrtf(s_m2[n]+EPSF); mx=fmaxf(mx,lg[n]); }
      float ssum=0.f;
      for (int n=0;n<Nz;n++){ lg[n]=expf(lg[n]-mx); ssum+=lg[n]; }
      for (int n=0;n<Nz;n++){
        float crn = lg[n]/ssum;
        s_wr[r*Nz+n] = s_sc[7+r*3+0]*s_bwd[r*Nz+n] + s_sc[7+r*3+1]*crn + s_sc[7+r*3+2]*s_fwd[r*Nz+n];
      }
    }
  }
  __syncthreads();

  // read vectors (write interleaved [kg][b][4]) + state writeback
  float* rbase = rT + (size_t)((t+1)&1)*RSLAB;
  for (int w = tid; w < Wz; w += NT){
    float m0=s_M[0*Wz+w], m1=s_M[1*Wz+w], m2=s_M[2*Wz+w], m3=s_M[3*Wz+w], m4=s_M[4*Wz+w];
    #pragma unroll
    for (int r=0;r<Rz;r++){
      float rv = s_wr[r*Nz+0]*m0 + s_wr[r*Nz+1]*m1 + s_wr[r*Nz+2]*m2
               + s_wr[r*Nz+3]*m3 + s_wr[r*Nz+4]*m4;
      int i = r*Wz + w;
      rbase[(size_t)(i>>2)*128 + b*4 + (i&3)] = rv;
    }
  }
  for (int i = tid; i < Nz*Wz; i += NT) Mg[(size_t)b*Nz*Wz+i] = s_M[i];
  if (tid < Nz){ ug[b*Nz+tid]=s_u[tid]; pg[b*Nz+tid]=s_p[tid]; wwg[b*Nz+tid]=s_ww[tid]; }
  if (tid < Nz*Nz) Lg[b*Nz*Nz+tid]=s_L[tid];
  if (tid < Rz*Nz) wrg[b*Rz*Nz+tid]=s_wr[tid];
}

__global__ void __launch_bounds__(NT, 1)
dnc_kernel(const int* __restrict__ src, const float* __restrict__ emb,
           const float* __restrict__ w_ih, const float* __restrict__ w_hh,
           const float* __restrict__ b_lstm,
           const float* __restrict__ w_xi, const float* __restrict__ b_xi,
           const float* __restrict__ w_out, const float* __restrict__ b_out,
           float* __restrict__ out, float* __restrict__ ws)
{
  cg::grid_group grid = cg::this_grid();
  const int tid = threadIdx.x;
  const int gid = blockIdx.x*NT + tid;

  float* embT  = ws;                                   // [T][128 kg][32 b][4]
  float* wxiT  = embT  + (size_t)Tz*HSLAB;             // [IF][H]
  float* woutT = wxiT  + (size_t)IFz*Hz;               // [H][XD]
  float* hT    = woutT + (size_t)Hz*XD;                // [2][128][32][4]
  float* cT    = hT    + 2*HSLAB;                      // [128][32][4]
  float* rT    = cT    + HSLAB;                        // [2][256][32][4]
  float* xiT   = rT    + 2*RSLAB;                      // [B][IF]
  float* Mg    = xiT   + (size_t)IFz*Bz;               // [B][N][W]
  float* ug    = Mg    + (size_t)Bz*Nz*Wz;             // [B][N]
  float* pg    = ug    + Bz*Nz;
  float* wwg   = pg    + Bz*Nz;
  float* Lg    = wwg   + Bz*Nz;                        // [B][N*N]
  float* wrg   = Lg    + Bz*Nz*Nz;                     // [B][R*N]

  // ---- phase 0: init / transposes / embedding gather (interleaved) ----
  {
    float4* embT4 = (float4*)embT;
    const float4* emb4 = (const float4*)emb;
    for (int i = gid; i < Tz*128*Bz; i += NTH){   // i = t*4096 + kg*32 + b
      int b = i & 31, kg = (i>>5) & 127, tt = i >> 12;
      embT4[i] = emb4[(size_t)src[b*Tz+tt]*128 + kg];
    }
  }
  for (size_t i = gid; i < (size_t)IFz*Hz; i += NTH){
    int k = (int)(i % Hz); size_t f = i / Hz;
    wxiT[i] = w_xi[(size_t)k*IFz + f];
  }
  for (size_t i = gid; i < (size_t)Hz*XD; i += NTH){
    int k = (int)(i % XD); int j = (int)(i / XD);
    woutT[i] = w_out[(size_t)k*Hz + j];
  }
  for (int i = gid; i < 2*HSLAB; i += NTH) hT[i]=0.f;
  for (int i = gid; i < HSLAB;   i += NTH) cT[i]=0.f;
  for (int i = gid; i < 2*RSLAB; i += NTH) rT[i]=0.f;
  for (int i = gid; i < Bz*Nz*Wz;i += NTH) Mg[i]=0.f;
  for (int i = gid; i < Bz*(3*Nz + Nz*Nz + Rz*Nz); i += NTH) ug[i]=0.f; // ug..wrg contiguous
  grid.sync();

  // ---- time loop ----
  for (int t = 0; t < Tz; ++t){
    const int cur = t & 1, nxt = (t+1)&1;

    // Phase A: gates GEMV + LSTM pointwise. thread=(gate,b,j); full 2048-dot.
    {
      const int gate = gid & 3;
      const int b    = (gid >> 2) & 31;
      const int j    = gid >> 7;
      const int row  = gate*Hz + j;
      const int b4   = b*4;
      const float* w1 = w_ih + (size_t)row*XD;
      const float* w2 = w_hh + (size_t)row*Hz;
      float acc = dotI(embT + (size_t)t*HSLAB + b4, w1,      128)
                + dotI(rT  + (size_t)cur*RSLAB + b4, w1+Hz,  256)
                + dotI(hT  + (size_t)cur*HSLAB + b4, w2,     128)
                + b_lstm[row];
      const int lane = tid & 63;
      const int bse  = lane & ~3;
      float gi = __shfl(acc, bse+0, 64);
      float gf = __shfl(acc, bse+1, 64);
      float gg = __shfl(acc, bse+2, 64);
      float go = __shfl(acc, bse+3, 64);
      if (gate == 0){
        const int ca = (j>>2)*128 + b4 + (j&3);
        float cv = cT[ca];
        float cn = sigf(gf)*cv + sigf(gi)*tanhf(gg);
        float hn = sigf(go)*tanhf(cn);
        cT[ca] = cn;
        hT[(size_t)nxt*HSLAB + ca] = hn;
      }
    }
    grid.sync();

    // Phase B: xi = h_new @ w_xi + b_xi. thread=(b,f), full 512-dot, 2 rounds.
    {
      const float* hb = hT + (size_t)nxt*HSLAB;
      for (int id = gid; id < IFz*Bz; id += NTH){
        const int b = id & 31, f = id >> 5;
        float acc = dotI(hb + b*4, wxiT + (size_t)f*Hz, 128);
        xiT[(size_t)b*IFz + f] = acc + b_xi[f];
      }
    }
    grid.sync();

    // Phase C: WGs 0..31 memops; WGs 32+ compute out(t-1) with 2-way K-split
    if (blockIdx.x < Bz){
      memops(blockIdx.x, t, xiT, Mg, ug, pg, wwg, Lg, wrg, rT);
    } else if (t > 0){
      const int id = (blockIdx.x - Bz)*NT + tid;
      if (id < 2*Hz*Bz){
        const int ks = id & 1;
        const int o  = id >> 1;
        const int b  = o & 31;
        const int j  = o >> 5;
        const float* wj = woutT + (size_t)j*XD;
        const float* hc = hT + (size_t)cur*HSLAB;
        const float* rc = rT + (size_t)cur*RSLAB;
        float acc;
        if (ks == 0) acc = dotI(hc + b*4, wj, 128) + dotI(rc + b*4, wj + Hz, 64);
        else         acc = dotI(rc + 64*128 + b*4, wj + Hz + 256, 192);
        acc += __shfl_xor(acc, 1, 64);
        if (ks == 0)
          out[(size_t)b*Tz*Hz + (size_t)(t-1)*Hz + j] = acc + b_out[j];
      }
    }
    grid.sync();
  }

  // ---- epilogue: out(T-1) (state in buffer 0), final h and c ----
  if (gid < 2*Hz*Bz){
    const int ks = gid & 1;
    const int o  = gid >> 1;
    const int b  = o & 31;
    const int j  = o >> 5;
    const float* wj = woutT + (size_t)j*XD;
    float acc;
    if (ks == 0) acc = dotI(hT + b*4, wj, 128) + dotI(rT + b*4, wj + Hz, 64);
    else         acc = dotI(rT + 64*128 + b*4, wj + Hz + 256, 192);
    acc += __shfl_xor(acc, 1, 64);
    if (ks == 0)
      out[(size_t)b*Tz*Hz + (size_t)(Tz-1)*Hz + j] = acc + b_out[j];
  }
  if (gid < Hz*Bz){
    const int b = gid & 31, j = gid >> 5;
    const int ca = (j>>2)*128 + b*4 + (j&3);
    out[(size_t)Bz*Tz*Hz + (size_t)b*Hz + j]                 = hT[ca];
    out[(size_t)Bz*Tz*Hz + (size_t)Bz*Hz + (size_t)b*Hz + j] = cT[ca];
  }
}

extern "C" void kernel_launch(void* const* d_in, const int* in_sizes, int n_in,
                              void* d_out, int out_size, void* d_ws, size_t ws_size,
                              hipStream_t stream)
{
  const int*   src    = (const int*)  d_in[0];
  // d_in[1] = source_lengths (unused by reference)
  const float* emb    = (const float*)d_in[2];
  const float* w_ih   = (const float*)d_in[3];
  const float* w_hh   = (const float*)d_in[4];
  const float* b_lstm = (const float*)d_in[5];
  const float* w_xi   = (const float*)d_in[6];
  const float* b_xi   = (const float*)d_in[7];
  const float* w_out  = (const float*)d_in[8];
  const float* b_out  = (const float*)d_in[9];
  float* out = (float*)d_out;
  float* ws  = (float*)d_ws;

  void* args[] = { &src, &emb, &w_ih, &w_hh, &b_lstm, &w_xi, &b_xi, &w_out, &b_out, &out, &ws };
  hipLaunchCooperativeKernel((const void*)dnc_kernel, dim3(NWG), dim3(NT), args, 0, stream);
}

// Round 5
// 34964.505 us; speedup vs baseline: 2.4864x; 1.5070x over previous
//
#include <hip/hip_runtime.h>

#define Bz 32
#define Tz 256
#define Hz 512
#define Nz 5
#define Rz 2
#define Wz 512
#define RWz 1024
#define XD 1536          // H + R*W
#define IFz 2573         // R*W + 3*W + 5*R + 3
#define EPSF 1e-6f
#define NWG 256
#define NT 256
#define NTH (NWG*NT)     // 65536

// interleaved state layout: [kg][b][4] ; slab stride per kg = 32*4 = 128 floats
#define HSLAB 16384      // 128 kg * 128
#define RSLAB 32768      // 256 kg * 128

// workspace float offsets (keep host memset in sync!)
#define WXIT_OFF (Tz*HSLAB)                            // 4194304
#define WOUT_OFF (WXIT_OFF + IFz*Hz)                   // 5511680
#define HT_OFF   (WOUT_OFF + Hz*XD)                    // 6298112
#define CT_OFF   (HT_OFF + 2*HSLAB)                    // 6330880
#define RT_OFF   (CT_OFF + HSLAB)                      // 6347264
#define XIT_OFF  (RT_OFF + 2*RSLAB)                    // 6412800
#define MG_OFF   (XIT_OFF + IFz*Bz)                    // 6495136
#define UG_OFF   (MG_OFF + Bz*Nz*Wz)                   // 6577056
#define BAR_OFF  (UG_OFF + 1600 + 32)                  // 6578688 (64-aligned)

// xi field offsets
#define O_KR 0
#define O_BR 1024
#define O_KW 1026
#define O_BW 1538
#define O_E  1539
#define O_V  2051
#define O_FG 2563
#define O_GA 2565
#define O_GW 2566
#define O_PI 2567

__device__ __forceinline__ float sigf(float x){ return 1.0f/(1.0f+expf(-x)); }
__device__ __forceinline__ float splus(float x){ return fmaxf(x,0.0f) + log1pf(expf(-fabsf(x))); }

// ---- custom grid barrier: 16 monotonic counters + generation flag ----
// bar[0..1023]: counters at stride 64 (256B); bar[1024]: generation.
__device__ __forceinline__ void gbar(unsigned* bar, unsigned k){
  __syncthreads();
  const int tid = threadIdx.x;
  const unsigned wg = blockIdx.x;
  if (tid == 0){
    __builtin_amdgcn_fence(__ATOMIC_RELEASE, "agent");
    __hip_atomic_fetch_add(&bar[(wg & 15u)*64], 1u, __ATOMIC_RELAXED, __HIP_MEMORY_SCOPE_AGENT);
  }
  if (wg == 0){
    if (tid < 16){
      const unsigned tgt = 16u*(k+1u);
      while (__hip_atomic_load(&bar[tid*64], __ATOMIC_RELAXED, __HIP_MEMORY_SCOPE_AGENT) < tgt)
        __builtin_amdgcn_s_sleep(1);
    }
    __syncthreads();
    if (tid == 0){
      __builtin_amdgcn_fence(__ATOMIC_ACQ_REL, "agent");
      __hip_atomic_store(&bar[1024], k+1u, __ATOMIC_RELAXED, __HIP_MEMORY_SCOPE_AGENT);
    }
    __syncthreads();
  } else {
    if (tid == 0){
      while (__hip_atomic_load(&bar[1024], __ATOMIC_RELAXED, __HIP_MEMORY_SCOPE_AGENT) < k+1u)
        __builtin_amdgcn_s_sleep(1);
      __builtin_amdgcn_fence(__ATOMIC_ACQUIRE, "agent");
    }
    __syncthreads();
  }
}

// x: interleaved state, pre-offset by b*4; walks kg slabs (stride 128 floats)
// w: contiguous row. nkg = number of float4 groups.
__device__ __forceinline__ float dotI(const float* __restrict__ x,
                                      const float* __restrict__ w, int nkg){
  const float4* w4 = (const float4*)w;
  float a0=0.f,a1=0.f,a2=0.f,a3=0.f;
  #pragma unroll 8
  for (int kg=0; kg<nkg; kg++){
    float4 xv = *(const float4*)(x + (size_t)kg*128);
    float4 wv = w4[kg];
    a0 = fmaf(xv.x,wv.x,a0); a1 = fmaf(xv.y,wv.y,a1);
    a2 = fmaf(xv.z,wv.z,a2); a3 = fmaf(xv.w,wv.w,a3);
  }
  return (a0+a1)+(a2+a3);
}

__device__ void memops(int b, int t, const float* xiT,
                       float* Mg, float* ug, float* pg, float* wwg, float* Lg, float* wrg,
                       float* rT)
{
  __shared__ float s_xi[IFz];
  __shared__ float s_M[Nz*Wz];
  __shared__ float s_u[Nz], s_p[Nz], s_ww[Nz], s_a[Nz], s_L[Nz*Nz], s_wr[Rz*Nz];
  __shared__ float s_sc[13]; // 0:br0 1:br1 2:bw 3:fg0 4:fg1 5:ga 6:gw 7..12:pi
  __shared__ float s_m2[Nz], s_dt[Nz], s_d0[Nz], s_d1[Nz];
  __shared__ float s_kw2, s_kr2[2];
  __shared__ float s_fwd[Rz*Nz], s_bwd[Rz*Nz];

  const int tid = threadIdx.x;
  const int wv = tid >> 6, ln = tid & 63;

  for (int f = tid; f < IFz; f += NT) s_xi[f] = xiT[(size_t)b*IFz + f];
  for (int i = tid; i < Nz*Wz; i += NT) s_M[i] = Mg[(size_t)b*Nz*Wz + i];
  if (tid < Nz){ s_u[tid]=ug[b*Nz+tid]; s_p[tid]=pg[b*Nz+tid]; s_ww[tid]=wwg[b*Nz+tid]; }
  if (tid < Nz*Nz) s_L[tid] = Lg[b*Nz*Nz+tid];
  if (tid < Rz*Nz) s_wr[tid] = wrg[b*Rz*Nz+tid];
  __syncthreads();

  if (tid == 0){
    s_sc[0] = 1.0f + splus(s_xi[O_BR+0]);
    s_sc[1] = 1.0f + splus(s_xi[O_BR+1]);
    s_sc[2] = 1.0f + splus(s_xi[O_BW]);
    s_sc[3] = sigf(s_xi[O_FG+0]);
    s_sc[4] = sigf(s_xi[O_FG+1]);
    s_sc[5] = sigf(s_xi[O_GA]);
    s_sc[6] = sigf(s_xi[O_GW]);
    for (int r=0;r<Rz;r++){
      float x0=s_xi[O_PI+r*3+0], x1=s_xi[O_PI+r*3+1], x2=s_xi[O_PI+r*3+2];
      float m = fmaxf(x0,fmaxf(x1,x2));
      float e0=expf(x0-m), e1=expf(x1-m), e2=expf(x2-m);
      float s = e0+e1+e2;
      s_sc[7+r*3+0]=e0/s; s_sc[7+r*3+1]=e1/s; s_sc[7+r*3+2]=e2/s;
    }
  }
  __syncthreads();

  // psi & usage update (uses OLD ww, OLD wr)
  if (tid < Nz){
    float psi = (1.0f - s_sc[3]*s_wr[0*Nz+tid]) * (1.0f - s_sc[4]*s_wr[1*Nz+tid]);
    float uu = s_u[tid], w = s_ww[tid];
    s_u[tid] = (uu + w - uu*w) * psi;
  }

  // cosine(M_old, kw): waves 0..3 -> n 0..3, wave 3 also kw2 after? (NT=256 => 4 waves)
  if (wv < 4){
    const int n = wv;
    float pd=0.f, pm=0.f;
    for (int w = ln; w < Wz; w += 64){
      float kv = s_xi[O_KW+w], mv = s_M[n*Wz+w];
      pd = fmaf(kv,mv,pd); pm = fmaf(mv,mv,pm);
    }
    for (int off=32; off; off>>=1){ pd += __shfl_down(pd,off,64); pm += __shfl_down(pm,off,64); }
    if (ln==0){ s_dt[n]=pd; s_m2[n]=pm; }
  }
  if (wv == 3){
    float p2=0.f;
    for (int w=ln; w<Wz; w+=64){ float kv=s_xi[O_KW+w]; p2=fmaf(kv,kv,p2); }
    for (int off=32; off; off>>=1) p2 += __shfl_down(p2,off,64);
    if (ln==0) s_kw2 = p2;
  }
  __syncthreads();
  if (wv == 0){
    const int n = 4;
    float pd=0.f, pm=0.f;
    for (int w = ln; w < Wz; w += 64){
      float kv = s_xi[O_KW+w], mv = s_M[n*Wz+w];
      pd = fmaf(kv,mv,pd); pm = fmaf(mv,mv,pm);
    }
    for (int off=32; off; off>>=1){ pd += __shfl_down(pd,off,64); pm += __shfl_down(pm,off,64); }
    if (ln==0){ s_dt[n]=pd; s_m2[n]=pm; }
  }
  __syncthreads();

  if (tid == 0){
    // allocation weights from updated u (stable ascending argsort, N=5)
    float su[Nz]; int idx[Nz];
    for (int i=0;i<Nz;i++){
      float v = EPSF + (1.0f-EPSF)*s_u[i];
      int j=i;
      while (j>0 && su[j-1] > v){ su[j]=su[j-1]; idx[j]=idx[j-1]; j--; }
      su[j]=v; idx[j]=i;
    }
    float cp = 1.0f;
    for (int k=0;k<Nz;k++){ s_a[idx[k]] = (1.0f - su[k])*cp; cp *= su[k]; }
    // content write weights
    float rk = rsqrtf(s_kw2 + EPSF);
    float lg[Nz], mx=-1e30f;
    for (int n=0;n<Nz;n++){ lg[n] = s_sc[2]*s_dt[n]*rk*rsqrtf(s_m2[n]+EPSF); mx=fmaxf(mx,lg[n]); }
    float ssum=0.f;
    for (int n=0;n<Nz;n++){ lg[n]=expf(lg[n]-mx); ssum+=lg[n]; }
    float ga=s_sc[5], gw=s_sc[6];
    for (int n=0;n<Nz;n++){ float cwn = lg[n]/ssum; s_ww[n] = gw*(ga*s_a[n] + (1.0f-ga)*cwn); }
  }
  __syncthreads();

  // memory write
  for (int i = tid; i < Nz*Wz; i += NT){
    int n = i >> 9, w = i & 511;
    float e = sigf(s_xi[O_E+w]);
    float v = s_xi[O_V+w];
    s_M[i] = s_M[i]*(1.0f - s_ww[n]*e) + s_ww[n]*v;
  }
  __syncthreads();

  // link matrix, precedence, fwd/bwd
  if (tid == 0){
    float wsum = 0.f;
    for (int n=0;n<Nz;n++) wsum += s_ww[n];
    float Lo[Nz*Nz];
    for (int i=0;i<Nz;i++)
      for (int j=0;j<Nz;j++)
        Lo[i*Nz+j] = (i==j) ? 0.0f : ((1.0f - s_ww[i] - s_ww[j])*s_L[i*Nz+j] + s_ww[i]*s_p[j]);
    for (int i=0;i<Nz*Nz;i++) s_L[i]=Lo[i];
    for (int j=0;j<Nz;j++) s_p[j] = (1.0f-wsum)*s_p[j] + s_ww[j];
    for (int r=0;r<Rz;r++)
      for (int n=0;n<Nz;n++){
        float f=0.f, bb=0.f;
        for (int m=0;m<Nz;m++){ f = fmaf(s_L[n*Nz+m], s_wr[r*Nz+m], f); bb = fmaf(s_L[m*Nz+n], s_wr[r*Nz+m], bb); }
        s_fwd[r*Nz+n]=f; s_bwd[r*Nz+n]=bb;
      }
  }
  __syncthreads();

  // cosine(M_new, kr): waves 0..3 -> n 0..3; then wave0 n=4; waves 1,2 ||kr||^2
  if (wv < 4){
    const int n = wv;
    float pm=0.f,p0=0.f,p1=0.f;
    for (int w=ln; w<Wz; w+=64){
      float mv=s_M[n*Wz+w];
      pm=fmaf(mv,mv,pm);
      p0=fmaf(s_xi[O_KR+w],    mv,p0);
      p1=fmaf(s_xi[O_KR+Wz+w], mv,p1);
    }
    for (int off=32; off; off>>=1){
      pm += __shfl_down(pm,off,64); p0 += __shfl_down(p0,off,64); p1 += __shfl_down(p1,off,64);
    }
    if (ln==0){ s_m2[n]=pm; s_d0[n]=p0; s_d1[n]=p1; }
  }
  __syncthreads();
  if (wv == 0){
    const int n = 4;
    float pm=0.f,p0=0.f,p1=0.f;
    for (int w=ln; w<Wz; w+=64){
      float mv=s_M[n*Wz+w];
      pm=fmaf(mv,mv,pm);
      p0=fmaf(s_xi[O_KR+w],    mv,p0);
      p1=fmaf(s_xi[O_KR+Wz+w], mv,p1);
    }
    for (int off=32; off; off>>=1){
      pm += __shfl_down(pm,off,64); p0 += __shfl_down(p0,off,64); p1 += __shfl_down(p1,off,64);
    }
    if (ln==0){ s_m2[n]=pm; s_d0[n]=p0; s_d1[n]=p1; }
  } else if (wv == 1 || wv == 2){
    const int r = wv - 1;
    float p2=0.f;
    for (int w=ln; w<Wz; w+=64){ float kv=s_xi[O_KR+r*Wz+w]; p2=fmaf(kv,kv,p2); }
    for (int off=32; off; off>>=1) p2 += __shfl_down(p2,off,64);
    if (ln==0) s_kr2[r]=p2;
  }
  __syncthreads();

  if (tid == 0){
    for (int r=0;r<Rz;r++){
      float rk = rsqrtf(s_kr2[r]+EPSF);
      const float* dd = (r==0) ? s_d0 : s_d1;
      float br = s_sc[r];
      float lg[Nz], mx=-1e30f;
      for (int n=0;n<Nz;n++){ lg[n] = br*dd[n]*rk*rsqrtf(s_m2[n]+EPSF); mx=fmaxf(mx,lg[n]); }
      float ssum=0.f;
      for (int n=0;n<Nz;n++){ lg[n]=expf(lg[n]-mx); ssum+=lg[n]; }
      for (int n=0;n<Nz;n++){
        float crn = lg[n]/ssum;
        s_wr[r*Nz+n] = s_sc[7+r*3+0]*s_bwd[r*Nz+n] + s_sc[7+r*3+1]*crn + s_sc[7+r*3+2]*s_fwd[r*Nz+n];
      }
    }
  }
  __syncthreads();

  // read vectors (write interleaved [kg][b][4]) + state writeback
  float* rbase = rT + (size_t)((t+1)&1)*RSLAB;
  for (int w = tid; w < Wz; w += NT){
    float m0=s_M[0*Wz+w], m1=s_M[1*Wz+w], m2=s_M[2*Wz+w], m3=s_M[3*Wz+w], m4=s_M[4*Wz+w];
    #pragma unroll
    for (int r=0;r<Rz;r++){
      float rv = s_wr[r*Nz+0]*m0 + s_wr[r*Nz+1]*m1 + s_wr[r*Nz+2]*m2
               + s_wr[r*Nz+3]*m3 + s_wr[r*Nz+4]*m4;
      int i = r*Wz + w;
      rbase[(size_t)(i>>2)*128 + b*4 + (i&3)] = rv;
    }
  }
  for (int i = tid; i < Nz*Wz; i += NT) Mg[(size_t)b*Nz*Wz+i] = s_M[i];
  if (tid < Nz){ ug[b*Nz+tid]=s_u[tid]; pg[b*Nz+tid]=s_p[tid]; wwg[b*Nz+tid]=s_ww[tid]; }
  if (tid < Nz*Nz) Lg[b*Nz*Nz+tid]=s_L[tid];
  if (tid < Rz*Nz) wrg[b*Rz*Nz+tid]=s_wr[tid];
}

__global__ void __launch_bounds__(NT, 1)
dnc_kernel(const int* __restrict__ src, const float* __restrict__ emb,
           const float* __restrict__ w_ih, const float* __restrict__ w_hh,
           const float* __restrict__ b_lstm,
           const float* __restrict__ w_xi, const float* __restrict__ b_xi,
           const float* __restrict__ w_out, const float* __restrict__ b_out,
           float* __restrict__ out, float* __restrict__ ws)
{
  const int tid = threadIdx.x;
  const int gid = blockIdx.x*NT + tid;

  float* embT  = ws;                       // [T][128 kg][32 b][4]
  float* wxiT  = ws + WXIT_OFF;            // [IF][H]
  float* woutT = ws + WOUT_OFF;            // [H][XD]
  float* hT    = ws + HT_OFF;              // [2][128][32][4]
  float* cT    = ws + CT_OFF;              // [128][32][4]
  float* rT    = ws + RT_OFF;              // [2][256][32][4]
  float* xiT   = ws + XIT_OFF;             // [B][IF]
  float* Mg    = ws + MG_OFF;              // [B][N][W]
  float* ug    = ws + UG_OFF;              // [B][N]
  float* pg    = ug + Bz*Nz;
  float* wwg   = pg + Bz*Nz;
  float* Lg    = wwg + Bz*Nz;              // [B][N*N]
  float* wrg   = Lg + Bz*Nz*Nz;            // [B][R*N]
  unsigned* bar = (unsigned*)(ws + BAR_OFF);
  unsigned kbar = 0;

  // ---- phase 0: init / transposes / embedding gather (interleaved) ----
  {
    float4* embT4 = (float4*)embT;
    const float4* emb4 = (const float4*)emb;
    for (int i = gid; i < Tz*128*Bz; i += NTH){   // i = t*4096 + kg*32 + b
      int b = i & 31, kg = (i>>5) & 127, tt = i >> 12;
      embT4[i] = emb4[(size_t)src[b*Tz+tt]*128 + kg];
    }
  }
  for (size_t i = gid; i < (size_t)IFz*Hz; i += NTH){
    int k = (int)(i % Hz); size_t f = i / Hz;
    wxiT[i] = w_xi[(size_t)k*IFz + f];
  }
  for (size_t i = gid; i < (size_t)Hz*XD; i += NTH){
    int k = (int)(i % XD); int j = (int)(i / XD);
    woutT[i] = w_out[(size_t)k*Hz + j];
  }
  for (int i = gid; i < 2*HSLAB; i += NTH) hT[i]=0.f;
  for (int i = gid; i < HSLAB;   i += NTH) cT[i]=0.f;
  for (int i = gid; i < 2*RSLAB; i += NTH) rT[i]=0.f;
  for (int i = gid; i < Bz*Nz*Wz;i += NTH) Mg[i]=0.f;
  for (int i = gid; i < Bz*(3*Nz + Nz*Nz + Rz*Nz); i += NTH) ug[i]=0.f; // ug..wrg contiguous
  gbar(bar, kbar); kbar++;

  // ---- time loop ----
  for (int t = 0; t < Tz; ++t){
    const int cur = t & 1, nxt = (t+1)&1;

    // Phase A: gates GEMV + LSTM pointwise. thread=(gate,b,j); full 2048-dot.
    {
      const int gate = gid & 3;
      const int b    = (gid >> 2) & 31;
      const int j    = gid >> 7;
      const int row  = gate*Hz + j;
      const int b4   = b*4;
      const float* w1 = w_ih + (size_t)row*XD;
      const float* w2 = w_hh + (size_t)row*Hz;
      float acc = dotI(embT + (size_t)t*HSLAB + b4, w1,      128)
                + dotI(rT  + (size_t)cur*RSLAB + b4, w1+Hz,  256)
                + dotI(hT  + (size_t)cur*HSLAB + b4, w2,     128)
                + b_lstm[row];
      const int lane = tid & 63;
      const int bse  = lane & ~3;
      float gi = __shfl(acc, bse+0, 64);
      float gf = __shfl(acc, bse+1, 64);
      float gg = __shfl(acc, bse+2, 64);
      float go = __shfl(acc, bse+3, 64);
      if (gate == 0){
        const int ca = (j>>2)*128 + b4 + (j&3);
        float cv = cT[ca];
        float cn = sigf(gf)*cv + sigf(gi)*tanhf(gg);
        float hn = sigf(go)*tanhf(cn);
        cT[ca] = cn;
        hT[(size_t)nxt*HSLAB + ca] = hn;
      }
    }
    gbar(bar, kbar); kbar++;

    // Phase B: xi = h_new @ w_xi + b_xi. thread=(b,f), full 512-dot.
    {
      const float* hb = hT + (size_t)nxt*HSLAB;
      for (int id = gid; id < IFz*Bz; id += NTH){
        const int b = id & 31, f = id >> 5;
        float acc = dotI(hb + b*4, wxiT + (size_t)f*Hz, 128);
        xiT[(size_t)b*IFz + f] = acc + b_xi[f];
      }
    }
    gbar(bar, kbar); kbar++;

    // Phase C: WGs 0..31 memops; WGs 32+ compute out(t-1) with 2-way K-split
    if (blockIdx.x < Bz){
      memops(blockIdx.x, t, xiT, Mg, ug, pg, wwg, Lg, wrg, rT);
    } else if (t > 0){
      const int id = (blockIdx.x - Bz)*NT + tid;
      if (id < 2*Hz*Bz){
        const int ks = id & 1;
        const int o  = id >> 1;
        const int b  = o & 31;
        const int j  = o >> 5;
        const float* wj = woutT + (size_t)j*XD;
        const float* hc = hT + (size_t)cur*HSLAB;
        const float* rc = rT + (size_t)cur*RSLAB;
        float acc;
        if (ks == 0) acc = dotI(hc + b*4, wj, 128) + dotI(rc + b*4, wj + Hz, 64);
        else         acc = dotI(rc + 64*128 + b*4, wj + Hz + 256, 192);
        acc += __shfl_xor(acc, 1, 64);
        if (ks == 0)
          out[(size_t)b*Tz*Hz + (size_t)(t-1)*Hz + j] = acc + b_out[j];
      }
    }
    gbar(bar, kbar); kbar++;
  }

  // ---- epilogue: out(T-1) (state in buffer 0), final h and c ----
  if (gid < 2*Hz*Bz){
    const int ks = gid & 1;
    const int o  = gid >> 1;
    const int b  = o & 31;
    const int j  = o >> 5;
    const float* wj = woutT + (size_t)j*XD;
    float acc;
    if (ks == 0) acc = dotI(hT + b*4, wj, 128) + dotI(rT + b*4, wj + Hz, 64);
    else         acc = dotI(rT + 64*128 + b*4, wj + Hz + 256, 192);
    acc += __shfl_xor(acc, 1, 64);
    if (ks == 0)
      out[(size_t)b*Tz*Hz + (size_t)(Tz-1)*Hz + j] = acc + b_out[j];
  }
  if (gid < Hz*Bz){
    const int b = gid & 31, j = gid >> 5;
    const int ca = (j>>2)*128 + b*4 + (j&3);
    out[(size_t)Bz*Tz*Hz + (size_t)b*Hz + j]                 = hT[ca];
    out[(size_t)Bz*Tz*Hz + (size_t)Bz*Hz + (size_t)b*Hz + j] = cT[ca];
  }
}

extern "C" void kernel_launch(void* const* d_in, const int* in_sizes, int n_in,
                              void* d_out, int out_size, void* d_ws, size_t ws_size,
                              hipStream_t stream)
{
  const int*   src    = (const int*)  d_in[0];
  // d_in[1] = source_lengths (unused by reference)
  const float* emb    = (const float*)d_in[2];
  const float* w_ih   = (const float*)d_in[3];
  const float* w_hh   = (const float*)d_in[4];
  const float* b_lstm = (const float*)d_in[5];
  const float* w_xi   = (const float*)d_in[6];
  const float* b_xi   = (const float*)d_in[7];
  const float* w_out  = (const float*)d_in[8];
  const float* b_out  = (const float*)d_in[9];
  float* out = (float*)d_out;
  float* ws  = (float*)d_ws;

  // zero the barrier region (counters + generation) every call: deterministic
  // across graph replays, stream-ordered, capture-safe.
  hipMemsetAsync((char*)d_ws + (size_t)BAR_OFF*4, 0, 4608, stream);

  void* args[] = { &src, &emb, &w_ih, &w_hh, &b_lstm, &w_xi, &b_xi, &w_out, &b_out, &out, &ws };
  hipLaunchCooperativeKernel((const void*)dnc_kernel, dim3(NWG), dim3(NT), args, 0, stream);
}